// Round 14
// baseline (16.361 us; speedup 1.0000x reference)
//
#include <hip/hip_runtime.h>
#include <math.h>

#define H 4096
#define NSTEPS 1000
#define NT 512
#define NGATEBLK 12            // 3 gates x 4 contiguous quarters
#define NWLBLK 7
#define NREPACK (NGATEBLK + NWLBLK)   // 19 repack blocks; block 19 = solver
#define MAGIC 0x5A17C0DEull

typedef float f32x2 __attribute__((ext_vector_type(2)));

// ws layout: u64 rows [0,38) x 512 cols: rows 0..23 gate-folded weights,
// rows 24..37 W_lin. u32 rows [0,12): folded biases. flags: 19 u64 at ws+512KB.
// All ws traffic = relaxed AGENT-scope atomics (sc1); no fences (r6-proven).

__device__ __forceinline__ unsigned short f2bf(float f) {
    unsigned u = __builtin_bit_cast(unsigned, f);
    u += 0x7FFFu + ((u >> 16) & 1u);
    return (unsigned short)(u >> 16);
}
__device__ __forceinline__ float bf2f(unsigned h) {
    unsigned u = h << 16;
    return __builtin_bit_cast(float, u);
}
__device__ __forceinline__ unsigned long long pack4(float a, float b, float c, float d) {
    return (unsigned long long)f2bf(a) | ((unsigned long long)f2bf(b) << 16)
         | ((unsigned long long)f2bf(c) << 32) | ((unsigned long long)f2bf(d) << 48);
}
__device__ __forceinline__ unsigned pack2(float a, float b) {
    return (unsigned)f2bf(a) | ((unsigned)f2bf(b) << 16);
}

// packed-pair activations, |z| <= ~0.4 regime
__device__ __forceinline__ f32x2 sig3(f32x2 z) {
    f32x2 z2 = z * z;
    f32x2 p = z2 * (-1.0f / 48.0f) + 0.25f;
    return z * p + 0.5f;
}
__device__ __forceinline__ f32x2 tanh7(f32x2 z) {
    f32x2 z2 = z * z;
    f32x2 p = z2 * (-0.0539682540f) + 0.1333333333f;
    p = z2 * p + (-0.3333333333f);
    return (z * z2) * p + z;
}
__device__ __forceinline__ f32x2 tanh3(f32x2 z) {
    f32x2 z2 = z * z;
    f32x2 p = z2 * (-0.3333333333f) + 1.0f;
    return z * p;
}
__device__ __forceinline__ float poly_tanh(float z) {
    float z2 = z * z;
    float p = fmaf(z2, -0.0539682540f, 0.1333333333f);
    p = fmaf(z2, p, -0.3333333333f);
    return fmaf(z * z2, p, z);
}
__device__ __forceinline__ float poly_exp(float z) {
    float p = fmaf(z, 0.0083333333f, 0.0416666667f);
    p = fmaf(z, p, 0.1666666667f);
    p = fmaf(z, p, 0.5f);
    p = fmaf(z, p, 1.0f);
    return fmaf(z, p, 1.0f);
}
// packed tail variants (per-component identical op sequences)
__device__ __forceinline__ f32x2 poly_exp2(f32x2 z) {
    f32x2 p = z * 0.0083333333f + 0.0416666667f;
    p = z * p + 0.1666666667f;
    p = z * p + 0.5f;
    p = z * p + 1.0f;
    return z * p + 1.0f;
}

// ---- verified lane exchanges ONLY (r12 lesson: no guessed semantics) ----
// DPP quad_perm (GCN3-documented): xor1 = [1,0,3,2] = 0xB1, xor2 = [2,3,0,1] = 0x4E.
template<int CTRL>
__device__ __forceinline__ float dpp_x(float x) {
    int i = __builtin_bit_cast(int, x);
    int r = __builtin_amdgcn_update_dpp(i, i, CTRL, 0xF, 0xF, false);
    return __builtin_bit_cast(float, r);
}
// xor4 via ds_swizzle BitMode (ISA-doc encoding: (4<<10)|0x1F = 0x101F)
__device__ __forceinline__ float swz_xor4(float x) {
    int i = __builtin_bit_cast(int, x);
    int r = __builtin_amdgcn_ds_swizzle(i, 0x101F);
    return __builtin_bit_cast(float, r);
}
// merge-reduce pair step (tree shape identical to r10's shfl version)
template<int M, int CTRL>
__device__ __forceinline__ float mergep_dpp(float aE, float aO, int lane) {
    float u = (lane & M) ? aE : aO;
    float w = dpp_x<CTRL>(u);
    float base = (lane & M) ? aO : aE;
    return base + w;
}
__device__ __forceinline__ float rdlane(float v, int l) {
    return __builtin_bit_cast(float, __builtin_amdgcn_readlane(__builtin_bit_cast(int, v), l));
}

__global__ __launch_bounds__(NT, 1) void sketch_fused(
    const float* __restrict__ W_ih,
    const float* __restrict__ b_ih,
    const float* __restrict__ b_hh,
    const float* __restrict__ W_lin,
    const float* __restrict__ b_lin,
    const float* __restrict__ noise,
    float* __restrict__ out,
    unsigned char* __restrict__ ws)
{
    unsigned long long* ws8 = (unsigned long long*)ws;
    unsigned* wsu = (unsigned*)(ws + (size_t)38 * 512 * 8);
    unsigned long long* flags = (unsigned long long*)(ws + (512u << 10));
    const int tid = threadIdx.x;
    const int blk = blockIdx.x;

    if (blk < NREPACK) {
        if (blk < NGATEBLK) {
            // ---- gate repacker: contiguous quarter of one gate, float2 reads ----
            const int g = blk >> 2, p = blk & 3;
            const int up = p * 512 + tid;
            const int s  = up >> 2;
            const int j  = up & 3;
            const size_t f2w = (g == 0) ? 0 : (g == 1 ? (size_t)5 * H : (size_t)15 * H / 2);
            const float2* Wf2 = (const float2*)W_ih;
            float2 A  = Wf2[f2w + 5 * (size_t)up + 0];
            float2 Bv = Wf2[f2w + 5 * (size_t)up + 1];
            float2 Cc = Wf2[f2w + 5 * (size_t)up + 2];
            float2 D  = Wf2[f2w + 5 * (size_t)up + 3];
            float2 E  = Wf2[f2w + 5 * (size_t)up + 4];
            const size_t f2b = (g == 0) ? 0 : (g == 1 ? (size_t)H : (size_t)3 * H / 2);
            float2 bi = ((const float2*)b_ih)[f2b + up];
            float2 bh = ((const float2*)b_hh)[f2b + up];
            float b0 = bi.x + bh.x + Cc.x;         // bias + w4 fold
            float b1 = bi.y + bh.y + E.y;
            unsigned long long wA = pack4(A.x, Cc.y, A.y, D.x);
            unsigned long long wB = pack4(Bv.x - Cc.x, D.y - E.y, Bv.y - Cc.x, E.x - E.y);
            const int rA = g * 8 + 2 * j;
            __hip_atomic_store(&ws8[(size_t)rA * 512 + s],       wA, __ATOMIC_RELAXED, __HIP_MEMORY_SCOPE_AGENT);
            __hip_atomic_store(&ws8[(size_t)(rA + 1) * 512 + s], wB, __ATOMIC_RELAXED, __HIP_MEMORY_SCOPE_AGENT);
            __hip_atomic_store(&wsu[(size_t)(g * 4 + j) * 512 + s], pack2(b0, b1),
                               __ATOMIC_RELAXED, __HIP_MEMORY_SCOPE_AGENT);
        } else {
            // ---- W_lin repacker: one logit row, float4 reads ----
            const int l = blk - NGATEBLK;
            const float4* p4 = (const float4*)(W_lin + (size_t)l * H);
            float4 v0 = p4[2 * tid], v1 = p4[2 * tid + 1];
            unsigned long long wA = pack4(v0.x, v0.y, v0.z, v0.w);
            unsigned long long wB = pack4(v1.x, v1.y, v1.z, v1.w);
            __hip_atomic_store(&ws8[(size_t)(24 + 2 * l) * 512 + tid], wA, __ATOMIC_RELAXED, __HIP_MEMORY_SCOPE_AGENT);
            __hip_atomic_store(&ws8[(size_t)(25 + 2 * l) * 512 + tid], wB, __ATOMIC_RELAXED, __HIP_MEMORY_SCOPE_AGENT);
        }
        asm volatile("s_waitcnt vmcnt(0)" ::: "memory");
        __syncthreads();
        if (tid == 0)
            __hip_atomic_store(&flags[blk], MAGIC, __ATOMIC_RELAXED, __HIP_MEMORY_SCOPE_AGENT);
        return;
    }

    // ---------------- solver block ----------------
    const int lane = tid & 63;
    const int wave = tid >> 6;                 // 8 waves

    __shared__ __align__(16) float s_noise[NSTEPS * 2];
    __shared__ __align__(16) float s_part[2][8][8];   // [parity][LOGIT][wave] (transposed)

    if (tid < 500)
        ((float4*)s_noise)[tid] = ((const float4*)noise)[tid];
    if (tid < 16) s_part[tid & 1][7][tid >> 1] = 0.f;   // zero logit-7 row, both parities

    // float4 zero-fill of out; first vector = row-0 prefix [0,0,1,0]
    {
        float4* o4 = (float4*)out;
        for (int i = tid; i < 1251; i += NT)
            o4[i] = (i == 0) ? make_float4(0.f, 0.f, 1.f, 0.f) : make_float4(0.f, 0.f, 0.f, 0.f);
        if (tid == 0) out[5004] = 0.f;
    }

    if (wave == 0 && lane < NREPACK) {
        int guard = 0;
        while (__hip_atomic_load(&flags[lane], __ATOMIC_RELAXED, __HIP_MEMORY_SCOPE_AGENT) != MAGIC) {
            __builtin_amdgcn_s_sleep(2);
            if (++guard > (1 << 26)) break;
        }
    }
    __syncthreads();

    // ---- register-resident packed weights (sc1 u64/u32 loads, r8-proven) ----
    f32x2 Wg[3][4][4];
    f32x2 Bg[3][4];
    f32x2 WL[7][4];
    {
        unsigned long long raw[19];
#pragma unroll
        for (int r = 0; r < 19; ++r)
            raw[r] = __hip_atomic_load(&ws8[(size_t)r * 512 + tid], __ATOMIC_RELAXED, __HIP_MEMORY_SCOPE_AGENT);
#pragma unroll
        for (int r = 0; r < 19; ++r) {
            unsigned lo = (unsigned)raw[r], hi = (unsigned)(raw[r] >> 32);
            f32x2 e01 = {bf2f(lo & 0xFFFFu), bf2f(lo >> 16)};
            f32x2 e23 = {bf2f(hi & 0xFFFFu), bf2f(hi >> 16)};
            const int g = r >> 3, j = (r & 7) >> 1, isB = r & 1;
            Wg[g][isB ? 2 : 0][j] = e01;
            Wg[g][isB ? 3 : 1][j] = e23;
        }
#pragma unroll
        for (int r = 19; r < 38; ++r)
            raw[r - 19] = __hip_atomic_load(&ws8[(size_t)r * 512 + tid], __ATOMIC_RELAXED, __HIP_MEMORY_SCOPE_AGENT);
#pragma unroll
        for (int r = 19; r < 38; ++r) {
            unsigned lo = (unsigned)raw[r - 19], hi = (unsigned)(raw[r - 19] >> 32);
            f32x2 e01 = {bf2f(lo & 0xFFFFu), bf2f(lo >> 16)};
            f32x2 e23 = {bf2f(hi & 0xFFFFu), bf2f(hi >> 16)};
            if (r < 24) {
                const int g = r >> 3, j = (r & 7) >> 1, isB = r & 1;
                Wg[g][isB ? 2 : 0][j] = e01;
                Wg[g][isB ? 3 : 1][j] = e23;
            } else {
                const int m = r - 24, l = m >> 1, h = m & 1;
                WL[l][2 * h]     = e01;
                WL[l][2 * h + 1] = e23;
            }
        }
        unsigned rawb[12];
#pragma unroll
        for (int r = 0; r < 12; ++r)
            rawb[r] = __hip_atomic_load(&wsu[(size_t)r * 512 + tid], __ATOMIC_RELAXED, __HIP_MEMORY_SCOPE_AGENT);
#pragma unroll
        for (int r = 0; r < 12; ++r) {
            f32x2 e = {bf2f(rawb[r] & 0xFFFFu), bf2f(rawb[r] >> 16)};
            Bg[r >> 2][r & 3] = e;
        }
    }
    // b_lin: uniform scalar loads (7 floats)
    const float bl0 = b_lin[0], bl1 = b_lin[1], bl2 = b_lin[2], bl3 = b_lin[3];
    const float bl4 = b_lin[4], bl5 = b_lin[5], bl6 = b_lin[6];

    // prev state: x, y, p0, p1 (p2 folded); uniform in registers across all threads
    float pv0 = 0.f, pv1 = 0.f, pv2 = 1.f, pv3 = 0.f;

    for (int t = 0; t < NSTEPS; ++t) {
        // issue the noise LDS reads early; latency hides under the FMA block
        const float n0 = s_noise[2 * t], n1 = s_noise[2 * t + 1];

        const f32x2 P0 = {pv0, pv0}, P1 = {pv1, pv1}, P2 = {pv2, pv2}, P3 = {pv3, pv3};
        f32x2 AC0 = {0.f, 0.f}, AC1 = AC0, AC2 = AC0, AC3 = AC0, AC4 = AC0, AC5 = AC0, AC6 = AC0;
#pragma unroll
        for (int j = 0; j < 4; ++j) {
            f32x2 gi = Wg[0][0][j] * P0 + Bg[0][j];
            gi = Wg[0][1][j] * P1 + gi;
            gi = Wg[0][2][j] * P2 + gi;
            gi = Wg[0][3][j] * P3 + gi;
            f32x2 gg = Wg[1][0][j] * P0 + Bg[1][j];
            gg = Wg[1][1][j] * P1 + gg;
            gg = Wg[1][2][j] * P2 + gg;
            gg = Wg[1][3][j] * P3 + gg;
            f32x2 go = Wg[2][0][j] * P0 + Bg[2][j];
            go = Wg[2][1][j] * P1 + go;
            go = Wg[2][2][j] * P2 + go;
            go = Wg[2][3][j] * P3 + go;
            f32x2 c = sig3(gi) * tanh7(gg);
            f32x2 h = sig3(go) * tanh3(c);
            AC0 = WL[0][j] * h + AC0;
            AC1 = WL[1][j] * h + AC1;
            AC2 = WL[2][j] * h + AC2;
            AC3 = WL[3][j] * h + AC3;
            AC4 = WL[4][j] * h + AC4;
            AC5 = WL[5][j] * h + AC5;
            AC6 = WL[6][j] * h + AC6;
        }
        float a0 = AC0.x + AC0.y, a1 = AC1.x + AC1.y, a2 = AC2.x + AC2.y;
        float a3 = AC3.x + AC3.y, a4 = AC4.x + AC4.y, a5 = AC5.x + AC5.y;
        float a6 = AC6.x + AC6.y;

        // in-wave merge stages: xor1/xor2 via DPP quad_perm, xor4 via ds_swizzle
        // (tree shape identical to r10); completion xor8/16/32 via r10-proven shfl.
        float r01 = mergep_dpp<1, 0xB1>(a0, a1, lane);
        float r23 = mergep_dpp<1, 0xB1>(a2, a3, lane);
        float r45 = mergep_dpp<1, 0xB1>(a4, a5, lane);
        float r66 = a6 + dpp_x<0xB1>(a6);
        float r03 = mergep_dpp<2, 0x4E>(r01, r23, lane);
        float r46 = mergep_dpp<2, 0x4E>(r45, r66, lane);
        float u = (lane & 4) ? r03 : r46;
        float w = swz_xor4(u);
        float rr = ((lane & 4) ? r46 : r03) + w;
        rr += __shfl_xor(rr, 8, 64);
        rr += __shfl_xor(rr, 16, 64);
        rr += __shfl_xor(rr, 32, 64);          // lane l = wave total of logit (l&7)

        const int lb = t & 1;
        if (lane < 7) s_part[lb][lane][wave] = rr;   // transposed: [logit][wave]
        __syncthreads();                       // the ONLY barrier per step
        // cross-wave: logit row is 32B contiguous -> 2x float4 + 7 local adds,
        // no cross-lane ops. Row 7 is zero.
        const float4 vlo = *(const float4*)&s_part[lb][lane & 7][0];
        const float4 vhi = *(const float4*)&s_part[lb][lane & 7][4];
        float v = ((vlo.x + vlo.y) + (vlo.z + vlo.w)) + ((vhi.x + vhi.y) + (vhi.z + vhi.w));

        // logits -> SGPRs; all lanes compute the tail redundantly (uniform),
        // packed in f32x2 pairs (r14: halves the serial tail op count).
        f32x2 s02 = {rdlane(v, 0) + bl0, rdlane(v, 2) + bl2};
        f32x2 s13 = {rdlane(v, 1) + bl1, rdlane(v, 3) + bl3};
        f32x2 s45 = {rdlane(v, 4) + bl4, rdlane(v, 5) + bl5};
        float s6  = rdlane(v, 6) + bl6;
        f32x2 q02 = tanh7(s02);
        f32x2 q13 = tanh7(s13);
        f32x2 q45 = tanh7(s45);
        float q6  = poly_tanh(s6);
        float mx  = fmaxf(q45.x, fmaxf(q45.y, q6));
        f32x2 e01 = poly_exp2(q45 - mx);       // {e0, e1}
        float e2  = poly_exp(q6 - mx);
        float inv = __fdividef(1.f, e01.x + e01.y + e2);
        float p0 = e01.x * inv, p1 = e01.y * inv, p2 = e2 * inv;
        f32x2 sc = poly_exp2(q13 * 0.5f);      // sample scales
        f32x2 nn = {n0, n1};
        f32x2 xx = sc * nn + q02;              // {x0, x1}
        if (tid == 0) {
            float* row = out + (t + 1) * 5;
            row[0] = xx.x; row[1] = xx.y; row[2] = p0; row[3] = p1; row[4] = p2;
        }
        pv0 = xx.x; pv1 = xx.y; pv2 = p0; pv3 = p1;
        // argmax(row[2:])==2 iff e2 strictly beats e0,e1 (first-index ties)
        if (e2 > e01.x && e2 > e01.y) break;   // uniform; later rows pre-zeroed
    }
}

extern "C" void kernel_launch(void* const* d_in, const int* in_sizes, int n_in,
                              void* d_out, int out_size, void* d_ws, size_t ws_size,
                              hipStream_t stream) {
    const float* W_ih  = (const float*)d_in[0];
    // d_in[1] = W_hh: mathematically dead (h = c = 0 every step) — never read.
    const float* b_ih  = (const float*)d_in[2];
    const float* b_hh  = (const float*)d_in[3];
    const float* W_lin = (const float*)d_in[4];
    const float* b_lin = (const float*)d_in[5];
    const float* noise = (const float*)d_in[6];
    float* out = (float*)d_out;

    hipLaunchKernelGGL(sketch_fused, dim3(NREPACK + 1), dim3(NT), 0, stream,
                       W_ih, b_ih, b_hh, W_lin, b_lin, noise, out,
                       (unsigned char*)d_ws);
}